// Round 2
// baseline (9710.048 us; speedup 1.0000x reference)
//
#include <hip/hip_runtime.h>
#include <hip/hip_bf16.h>
#include <math.h>

#define DEPTH 24
#define D_MODEL 192
#define D_INNER 384
#define D_STATE 16
#define DT_RANK 12
#define NCLS 1000
#define PATCHSZ 16
#define IMG 224
#define GSZ 14
#define L_TOK 196
#define BATCH 64
#define M_ROWS (BATCH*L_TOK)   // 12544
#define N_CH (BATCH*D_INNER)   // 24576 channels (b,d)
#define EPSV 1e-5f

// ---------------------------------------------------------------- utilities
__device__ __forceinline__ float silu_(float x) {
    return x / (1.f + __expf(-x));
}

// ---------------------------------------------------------------- im2col for patch embedding
__global__ __launch_bounds__(256) void im2col_k(const float* __restrict__ x,
                                                float* __restrict__ Acol) {
    int idx = blockIdx.x * 256 + threadIdx.x;
    if (idx >= M_ROWS * 768) return;
    int row = idx / 768, k = idx % 768;
    int b = row / L_TOK, l = row % L_TOK;
    int i = l / GSZ, j = l % GSZ;
    int c = k >> 8, r = k & 255, p = r >> 4, q = r & 15;
    Acol[idx] = x[((size_t)(b * 3 + c) * IMG + (i * PATCHSZ + p)) * IMG + (j * PATCHSZ + q)];
}

// ---------------------------------------------------------------- generic fp32 GEMM:  C[M,N] = A[M,K] * B[N,K]^T  (+bias, +softplus)
// act: 0 = none, 1 = +bias, 2 = +bias then softplus
__global__ __launch_bounds__(256) void gemm_nt(
    const float* __restrict__ A, int lda,
    const float* __restrict__ B, int ldb,
    float* __restrict__ C, int ldc,
    int M, int N, int K,
    const float* __restrict__ bias, int act)
{
    __shared__ float As[16][68];
    __shared__ float Bs[16][68];
    const int t = threadIdx.x;
    const int tx = t & 15, ty = t >> 4;
    const int bm = blockIdx.y * 64, bn = blockIdx.x * 64;
    float acc[4][4] = {};
    const int kk = t & 15, m0 = t >> 4;

    for (int k0 = 0; k0 < K; k0 += 16) {
        int gk = k0 + kk;
        bool kok = gk < K;
#pragma unroll
        for (int p = 0; p < 4; ++p) {
            int mm = m0 + p * 16;
            int gm = bm + mm;
            As[kk][mm] = (kok && gm < M) ? A[(size_t)gm * lda + gk] : 0.f;
            int gn = bn + mm;
            Bs[kk][mm] = (kok && gn < N) ? B[(size_t)gn * ldb + gk] : 0.f;
        }
        __syncthreads();
#pragma unroll
        for (int k = 0; k < 16; ++k) {
            float4 av = *(const float4*)&As[k][ty * 4];
            float4 bv = *(const float4*)&Bs[k][tx * 4];
            float a0 = av.x, a1 = av.y, a2 = av.z, a3 = av.w;
            float b0 = bv.x, b1 = bv.y, b2 = bv.z, b3 = bv.w;
            acc[0][0] += a0 * b0; acc[0][1] += a0 * b1; acc[0][2] += a0 * b2; acc[0][3] += a0 * b3;
            acc[1][0] += a1 * b0; acc[1][1] += a1 * b1; acc[1][2] += a1 * b2; acc[1][3] += a1 * b3;
            acc[2][0] += a2 * b0; acc[2][1] += a2 * b1; acc[2][2] += a2 * b2; acc[2][3] += a2 * b3;
            acc[3][0] += a3 * b0; acc[3][1] += a3 * b1; acc[3][2] += a3 * b2; acc[3][3] += a3 * b3;
        }
        __syncthreads();
    }
#pragma unroll
    for (int i2 = 0; i2 < 4; ++i2) {
        int gm = bm + ty * 4 + i2;
        if (gm >= M) continue;
#pragma unroll
        for (int j = 0; j < 4; ++j) {
            int gn = bn + tx * 4 + j;
            if (gn >= N) continue;
            float v = acc[i2][j];
            if (act >= 1 && bias) v += bias[gn];
            if (act == 2) v = (v > 20.f) ? v : log1pf(__expf(v));
            C[(size_t)gm * ldc + gn] = v;
        }
    }
}

// ---------------------------------------------------------------- fused residual add + LayerNorm
__global__ __launch_bounds__(256) void ln_resid_k(
    const float* __restrict__ hid, float* __restrict__ resid,
    float* __restrict__ hn, const float* __restrict__ w,
    const float* __restrict__ b, int add)
{
    int wave = threadIdx.x >> 6, lane = threadIdx.x & 63;
    int row = blockIdx.x * 4 + wave;
    if (row >= M_ROWS) return;
    const float* hr = hid + (size_t)row * D_MODEL;
    float* rr = resid + (size_t)row * D_MODEL;
    float v[3];
#pragma unroll
    for (int j = 0; j < 3; ++j) {
        int e = lane + 64 * j;
        float h = hr[e];
        if (add) h += rr[e];
        rr[e] = h;
        v[j] = h;
    }
    float s = v[0] + v[1] + v[2];
    float sq = v[0] * v[0] + v[1] * v[1] + v[2] * v[2];
#pragma unroll
    for (int m = 1; m < 64; m <<= 1) {
        s += __shfl_xor(s, m, 64);
        sq += __shfl_xor(sq, m, 64);
    }
    float mu = s * (1.f / 192.f);
    float var = sq * (1.f / 192.f) - mu * mu;
    float ve = var + EPSV;
    float rs = rsqrtf(ve);
    rs = rs * (1.5f - 0.5f * ve * rs * rs);
    float* hnr = hn + (size_t)row * D_MODEL;
#pragma unroll
    for (int j = 0; j < 3; ++j) {
        int e = lane + 64 * j;
        hnr[e] = (v[j] - mu) * rs * w[e] + b[e];
    }
}

// ---------------------------------------------------------------- depthwise causal conv (k=4) + SiLU
__global__ __launch_bounds__(256) void conv_silu_k(
    const float* __restrict__ xz, const float* __restrict__ cw,
    const float* __restrict__ cb, float* __restrict__ xc)
{
    int idx = blockIdx.x * 256 + threadIdx.x;
    if (idx >= M_ROWS * D_INNER) return;
    int d = idx % D_INNER;
    int row = idx / D_INNER;
    int l = row % L_TOK;
    float acc = cb[d];
    const float* cwd = cw + d * 4;
#pragma unroll
    for (int k = 0; k < 4; ++k) {
        int ls = l + k - 3;
        if (ls >= 0) acc += xz[(size_t)(row + k - 3) * 768 + d] * cwd[k];
    }
    xc[idx] = silu_(acc);
}

// ================================================================ chunked selective scan
// Channel ch = b*384+d. 16 lanes per (ch, chunk) group: one lane per state n.
// group linear id g: ch = g % N_CH, c = g / N_CH.

// ---- phase 1: per-chunk zero-state scan -> h_end, P (total decay product)
__global__ __launch_bounds__(256) void scan_p1(
    const float* __restrict__ delta, const float* __restrict__ xc,
    const float* __restrict__ dbc, const float* __restrict__ A_log,
    float* __restrict__ h_end, float* __restrict__ Pp, int clen)
{
    int g = blockIdx.x * 16 + (threadIdx.x >> 4);
    int n = threadIdx.x & 15;
    int ch = g % N_CH, c = g / N_CH;
    int b = ch / D_INNER, d = ch % D_INNER;
    float A = -__expf(A_log[d * D_STATE + n]);
    int l0 = c * clen;
    size_t row = (size_t)b * L_TOK + l0;
    const float* pd = delta + row * D_INNER + d;
    const float* px = xc + row * D_INNER + d;
    const float* pb = dbc + row * 44 + DT_RANK + n;

    float dl = *pd, xcv = *px, Bn = *pb;
    float h = 0.f, P = 1.f;
    for (int l = 0; l < clen; ++l) {
        int adv = (l + 1 < clen) ? 1 : 0;
        pd += adv * D_INNER; px += adv * D_INNER; pb += adv * 44;
        float dl_n = *pd, xc_n = *px, Bn_n = *pb;
        float dA = __expf(dl * A);
        h = dA * h + (dl * xcv) * Bn;
        P *= dA;
        dl = dl_n; xcv = xc_n; Bn = Bn_n;
    }
    size_t o = ((size_t)c * N_CH + ch) * D_STATE + n;
    h_end[o] = h;
    Pp[o] = P;
}

// ---- phase 2: cross-chunk prefix combine -> h_start per chunk
__global__ __launch_bounds__(256) void scan_p2(
    const float* __restrict__ h_end, const float* __restrict__ Pp,
    float* __restrict__ hs, int nchunk)
{
    int idx = blockIdx.x * 256 + threadIdx.x;   // (ch,n) flat, < N_CH*16
    if (idx >= N_CH * D_STATE) return;
    float H = 0.f;
    hs[idx] = 0.f;
    for (int c = 0; c < nchunk - 1; ++c) {
        size_t o = (size_t)c * N_CH * D_STATE + idx;
        H = Pp[o] * H + h_end[o];
        hs[(size_t)(c + 1) * N_CH * D_STATE + idx] = H;
    }
}

// ---- phase 3: true scan per chunk from h_start, emit y (fused +D*xc, *silu(z))
__global__ __launch_bounds__(256) void scan_p3(
    const float* __restrict__ delta, const float* __restrict__ xc,
    const float* __restrict__ dbc, const float* __restrict__ xz,
    const float* __restrict__ A_log, const float* __restrict__ Dp,
    const float* __restrict__ hs, float* __restrict__ y, int clen)
{
    int g = blockIdx.x * 16 + (threadIdx.x >> 4);
    int n = threadIdx.x & 15;
    int ch = g % N_CH, c = g / N_CH;
    int b = ch / D_INNER, d = ch % D_INNER;
    float A = -__expf(A_log[d * D_STATE + n]);
    float Dv = Dp[d];
    int l0 = c * clen;
    size_t row0 = (size_t)b * L_TOK + l0;
    const float* pd = delta + row0 * D_INNER + d;
    const float* px = xc + row0 * D_INNER + d;
    const float* pb = dbc + row0 * 44 + DT_RANK + n;
    const float* pz = xz + row0 * 768 + D_INNER + d;
    float* py = y + row0 * D_INNER + d;

    float h = hs ? hs[((size_t)c * N_CH + ch) * D_STATE + n] : 0.f;
    float dl = *pd, xcv = *px, Bn = *pb, Cn = pb[D_STATE], z = *pz;
    for (int l = 0; l < clen; ++l) {
        int adv = (l + 1 < clen) ? 1 : 0;
        pd += adv * D_INNER; px += adv * D_INNER; pb += adv * 44; pz += adv * 768;
        float dl_n = *pd, xc_n = *px, Bn_n = *pb, Cn_n = pb[D_STATE], z_n = *pz;
        float dA = __expf(dl * A);
        h = dA * h + (dl * xcv) * Bn;
        float p = h * Cn;
        p += __shfl_xor(p, 1);
        p += __shfl_xor(p, 2);
        p += __shfl_xor(p, 4);
        p += __shfl_xor(p, 8);
        if (n == 0) {
            *py = (p + Dv * xcv) * silu_(z);
        }
        py += D_INNER;
        dl = dl_n; xcv = xc_n; Bn = Bn_n; Cn = Cn_n; z = z_n;
    }
}

// ---------------------------------------------------------------- final LN on last token only
__global__ __launch_bounds__(64) void final_ln_k(
    const float* __restrict__ hid, const float* __restrict__ w,
    const float* __restrict__ b, float* __restrict__ feat)
{
    int bb = blockIdx.x;
    int lane = threadIdx.x;
    const float* hr = hid + ((size_t)bb * L_TOK + (L_TOK - 1)) * D_MODEL;
    float v[3];
#pragma unroll
    for (int j = 0; j < 3; ++j) v[j] = hr[lane + 64 * j];
    float s = v[0] + v[1] + v[2];
    float sq = v[0] * v[0] + v[1] * v[1] + v[2] * v[2];
#pragma unroll
    for (int m = 1; m < 64; m <<= 1) {
        s += __shfl_xor(s, m, 64);
        sq += __shfl_xor(sq, m, 64);
    }
    float mu = s * (1.f / 192.f);
    float var = sq * (1.f / 192.f) - mu * mu;
    float ve = var + EPSV;
    float rs = rsqrtf(ve);
    rs = rs * (1.5f - 0.5f * ve * rs * rs);
#pragma unroll
    for (int j = 0; j < 3; ++j) {
        int e = lane + 64 * j;
        feat[(size_t)bb * D_MODEL + e] = (v[j] - mu) * rs * w[e] + b[e];
    }
}

// ================================================================ host
extern "C" void kernel_launch(void* const* d_in, const int* in_sizes, int n_in,
                              void* d_out, int out_size, void* d_ws, size_t ws_size,
                              hipStream_t stream) {
    const float* x         = (const float*)d_in[0];
    const float* patch_w   = (const float*)d_in[1];
    const float* patch_b   = (const float*)d_in[2];
    const float* norm_w    = (const float*)d_in[3];
    const float* norm_b    = (const float*)d_in[4];
    const float* in_proj_w = (const float*)d_in[5];
    const float* conv_w    = (const float*)d_in[6];
    const float* conv_b    = (const float*)d_in[7];
    const float* x_proj_w  = (const float*)d_in[8];
    const float* dt_proj_w = (const float*)d_in[9];
    const float* dt_proj_b = (const float*)d_in[10];
    const float* A_log     = (const float*)d_in[11];
    const float* Dp        = (const float*)d_in[12];
    const float* out_proj_w= (const float*)d_in[13];
    const float* normf_w   = (const float*)d_in[14];
    const float* normf_b   = (const float*)d_in[15];
    const float* head_w    = (const float*)d_in[16];
    const float* head_b    = (const float*)d_in[17];
    float* out = (float*)d_out;

    // workspace layout (floats)
    float* ws    = (float*)d_ws;
    float* resid = ws;                       // 12544*192
    float* hid   = resid + (size_t)M_ROWS * D_MODEL;
    float* hn    = hid   + (size_t)M_ROWS * D_MODEL;
    float* xz    = hn    + (size_t)M_ROWS * D_MODEL;   // 12544*768, also im2col buffer
    float* xc    = xz    + (size_t)M_ROWS * 768;       // 12544*384
    float* dbc   = xc    + (size_t)M_ROWS * D_INNER;   // 12544*44
    float* delta = dbc   + (size_t)M_ROWS * 44;        // 12544*384
    float* ybuf  = delta + (size_t)M_ROWS * D_INNER;   // 12544*384
    float* feat  = ybuf  + (size_t)M_ROWS * D_INNER;   // 64*192
    float* scr   = feat  + (size_t)BATCH * D_MODEL;    // scan scratch

    // choose chunk count from available workspace
    size_t base_floats = (size_t)(scr - ws);
    size_t avail = (ws_size / 4 > base_floats) ? (ws_size / 4 - base_floats) : 0;
    int C = 1;
    const int cands[3] = {7, 4, 2};
    for (int ci = 0; ci < 3; ++ci) {
        size_t need = (size_t)cands[ci] * N_CH * D_STATE * 3;
        if (need <= avail) { C = cands[ci]; break; }
    }
    int clen = L_TOK / C;
    float* h_end = scr;                                     // C*N_CH*16
    float* Pp    = h_end + (size_t)C * N_CH * D_STATE;      // C*N_CH*16
    float* hs    = Pp    + (size_t)C * N_CH * D_STATE;      // C*N_CH*16

    // ---- patch embedding: im2col + GEMM -> hid
    im2col_k<<<(M_ROWS * 768) / 256, 256, 0, stream>>>(x, xz);
    {
        dim3 g((D_MODEL + 63) / 64, M_ROWS / 64);
        gemm_nt<<<g, 256, 0, stream>>>(xz, 768, patch_w, 768, hid, D_MODEL,
                                       M_ROWS, D_MODEL, 768, patch_b, 1);
    }

    // ---- 24 mamba layers
    for (int i = 0; i < DEPTH; ++i) {
        const float* nw  = norm_w    + (size_t)i * D_MODEL;
        const float* nb  = norm_b    + (size_t)i * D_MODEL;
        const float* iw  = in_proj_w + (size_t)i * 768 * D_MODEL;
        const float* cwp = conv_w    + (size_t)i * D_INNER * 4;
        const float* cbp = conv_b    + (size_t)i * D_INNER;
        const float* xw  = x_proj_w  + (size_t)i * 44 * D_INNER;
        const float* dtw = dt_proj_w + (size_t)i * D_INNER * DT_RANK;
        const float* dtb = dt_proj_b + (size_t)i * D_INNER;
        const float* al  = A_log     + (size_t)i * D_INNER * D_STATE;
        const float* dp  = Dp        + (size_t)i * D_INNER;
        const float* ow  = out_proj_w+ (size_t)i * D_MODEL * D_INNER;

        // residual + LN
        ln_resid_k<<<M_ROWS / 4, 256, 0, stream>>>(hid, resid, hn, nw, nb, i > 0 ? 1 : 0);

        // in_proj: xz[M,768] = hn @ iw^T
        {
            dim3 g(768 / 64, M_ROWS / 64);
            gemm_nt<<<g, 256, 0, stream>>>(hn, D_MODEL, iw, D_MODEL, xz, 768,
                                           M_ROWS, 768, D_MODEL, nullptr, 0);
        }
        // conv + silu -> xc
        conv_silu_k<<<(M_ROWS * D_INNER) / 256, 256, 0, stream>>>(xz, cwp, cbp, xc);
        // x_proj: dbc[M,44] = xc @ xw^T
        {
            dim3 g(1, M_ROWS / 64);
            gemm_nt<<<g, 256, 0, stream>>>(xc, D_INNER, xw, D_INNER, dbc, 44,
                                           M_ROWS, 44, D_INNER, nullptr, 0);
        }
        // dt_proj + softplus: delta[M,384] = softplus(dbc[:, :12] @ dtw^T + dtb)
        {
            dim3 g(D_INNER / 64, M_ROWS / 64);
            gemm_nt<<<g, 256, 0, stream>>>(dbc, 44, dtw, DT_RANK, delta, D_INNER,
                                           M_ROWS, D_INNER, DT_RANK, dtb, 2);
        }
        // chunked selective scan -> ybuf
        if (C > 1) {
            scan_p1<<<(N_CH * C) / 16, 256, 0, stream>>>(delta, xc, dbc, al, h_end, Pp, clen);
            scan_p2<<<(N_CH * D_STATE) / 256, 256, 0, stream>>>(h_end, Pp, hs, C);
            scan_p3<<<(N_CH * C) / 16, 256, 0, stream>>>(delta, xc, dbc, xz, al, dp, hs, ybuf, clen);
        } else {
            scan_p3<<<N_CH / 16, 256, 0, stream>>>(delta, xc, dbc, xz, al, dp, nullptr, ybuf, clen);
        }
        // out_proj: hid[M,192] = ybuf @ ow^T
        {
            dim3 g(D_MODEL / 64, M_ROWS / 64);
            gemm_nt<<<g, 256, 0, stream>>>(ybuf, D_INNER, ow, D_INNER, hid, D_MODEL,
                                           M_ROWS, D_MODEL, D_INNER, nullptr, 0);
        }
    }

    // ---- final LN (last token only) + head
    final_ln_k<<<BATCH, 64, 0, stream>>>(hid, normf_w, normf_b, feat);
    {
        dim3 g((NCLS + 63) / 64, (BATCH + 63) / 64);
        gemm_nt<<<g, 256, 0, stream>>>(feat, D_MODEL, head_w, D_MODEL, out, NCLS,
                                       BATCH, NCLS, D_MODEL, head_b, 1);
    }
}

// Round 3
// 4904.778 us; speedup vs baseline: 1.9797x; 1.9797x over previous
//
#include <hip/hip_runtime.h>
#include <hip/hip_bf16.h>
#include <math.h>

#define DEPTH 24
#define D_MODEL 192
#define D_INNER 384
#define D_STATE 16
#define DT_RANK 12
#define NCLS 1000
#define PATCHSZ 16
#define IMG 224
#define GSZ 14
#define L_TOK 196
#define BATCH 64
#define M_ROWS (BATCH*L_TOK)   // 12544
#define N_CH (BATCH*D_INNER)   // 24576
#define EPSV 1e-5f

typedef __attribute__((ext_vector_type(8))) short bf16x8;
typedef __attribute__((ext_vector_type(4))) float f32x4;
typedef unsigned short ushort_t;
typedef unsigned int uint_t;

__device__ __forceinline__ float silu_(float x) { return x / (1.f + __expf(-x)); }

__device__ __forceinline__ ushort_t f2bf(float f) {
    uint_t u = __float_as_uint(f);
    u += 0x7fffu + ((u >> 16) & 1u);       // RNE
    return (ushort_t)(u >> 16);
}

// ---------------------------------------------------------------- fp32 -> bf16 convert
__global__ __launch_bounds__(256) void f2bf_k(const float* __restrict__ s,
                                              ushort_t* __restrict__ d, int n) {
    for (int i = blockIdx.x * 256 + threadIdx.x; i < n; i += gridDim.x * 256)
        d[i] = f2bf(s[i]);
}

// ---------------------------------------------------------------- im2col (bf16 out)
__global__ __launch_bounds__(256) void im2col_k(const float* __restrict__ x,
                                                ushort_t* __restrict__ Acol) {
    int idx = blockIdx.x * 256 + threadIdx.x;
    if (idx >= M_ROWS * 768) return;
    int row = idx / 768, k = idx % 768;
    int b = row / L_TOK, l = row % L_TOK;
    int i = l / GSZ, j = l % GSZ;
    int c = k >> 8, r = k & 255, p = r >> 4, q = r & 15;
    Acol[idx] = f2bf(x[((size_t)(b * 3 + c) * IMG + (i * PATCHSZ + p)) * IMG + (j * PATCHSZ + q)]);
}

// ---------------------------------------------------------------- bf16 MFMA GEMM
// C[M,N] fp32 = A[M,K]bf16 * B[N,K]bf16^T (+bias).  M%128==0, N%64==0, K%32==0.
// block 256 thr = 4 waves (2x2), tile 128x64, BK=32.
__global__ __launch_bounds__(256) void gemm_mfma(
    const ushort_t* __restrict__ A, int lda,
    const ushort_t* __restrict__ B, int ldb,
    float* __restrict__ C, int ldc,
    int N, int K, const float* __restrict__ bias)
{
    __shared__ uint4 AlsU[512];   // 128 x 32 bf16, swizzled
    __shared__ uint4 BlsU[256];   // 64 x 32 bf16, swizzled
    char* Als = (char*)AlsU;
    char* Bls = (char*)BlsU;
    const int t = threadIdx.x;
    const int wid = t >> 6, lane = t & 63;
    const int wm = wid >> 1, wn = wid & 1;
    const int l15 = lane & 15, l4 = lane >> 4;
    const int bm = blockIdx.y * 128, bn = blockIdx.x * 64;

    f32x4 acc[4][2];
#pragma unroll
    for (int i = 0; i < 4; ++i)
#pragma unroll
        for (int j = 0; j < 2; ++j) acc[i][j] = (f32x4){0.f, 0.f, 0.f, 0.f};

    const int arow = t >> 2, akb = t & 3;   // staging coords
    for (int k0 = 0; k0 < K; k0 += 32) {
        // stage A: 512 chunks of 8 bf16 (16B), 2 iters
#pragma unroll
        for (int it = 0; it < 2; ++it) {
            int c = t + it * 256;
            int row = c >> 2, kb = c & 3;
            uint4 v = *(const uint4*)(A + (size_t)(bm + row) * lda + k0 + kb * 8);
            *(uint4*)(Als + row * 64 + ((kb ^ (row & 3)) << 4)) = v;
        }
        // stage B: 256 chunks
        {
            uint4 v = *(const uint4*)(B + (size_t)(bn + arow) * ldb + k0 + akb * 8);
            *(uint4*)(Bls + arow * 64 + ((akb ^ (arow & 3)) << 4)) = v;
        }
        __syncthreads();
        bf16x8 af[4], bfr[2];
#pragma unroll
        for (int fm = 0; fm < 4; ++fm) {
            int row = wm * 64 + fm * 16 + l15;
            af[fm] = *(const bf16x8*)(Als + row * 64 + ((l4 ^ (row & 3)) << 4));
        }
#pragma unroll
        for (int fn = 0; fn < 2; ++fn) {
            int row = wn * 32 + fn * 16 + l15;
            bfr[fn] = *(const bf16x8*)(Bls + row * 64 + ((l4 ^ (row & 3)) << 4));
        }
#pragma unroll
        for (int fm = 0; fm < 4; ++fm)
#pragma unroll
            for (int fn = 0; fn < 2; ++fn)
                acc[fm][fn] = __builtin_amdgcn_mfma_f32_16x16x32_bf16(af[fm], bfr[fn], acc[fm][fn], 0, 0, 0);
        __syncthreads();
    }
    // epilogue: row=(l>>4)*4+r, col=l&15 within each 16x16 frag
#pragma unroll
    for (int fm = 0; fm < 4; ++fm) {
#pragma unroll
        for (int fn = 0; fn < 2; ++fn) {
            int col = bn + wn * 32 + fn * 16 + l15;
            float bv = bias ? bias[col] : 0.f;
#pragma unroll
            for (int r = 0; r < 4; ++r) {
                int row = bm + wm * 64 + fm * 16 + l4 * 4 + r;
                C[(size_t)row * ldc + col] = acc[fm][fn][r] + bv;
            }
        }
    }
}

// ---------------------------------------------------------------- generic fp32 GEMM (small ops): C = A*B^T (+bias, +softplus)
__global__ __launch_bounds__(256) void gemm_nt(
    const float* __restrict__ A, int lda,
    const float* __restrict__ B, int ldb,
    float* __restrict__ C, int ldc,
    int M, int N, int K,
    const float* __restrict__ bias, int act)
{
    __shared__ float As[16][68];
    __shared__ float Bs[16][68];
    const int t = threadIdx.x;
    const int tx = t & 15, ty = t >> 4;
    const int bm = blockIdx.y * 64, bn = blockIdx.x * 64;
    float acc[4][4] = {};
    const int kk = t & 15, m0 = t >> 4;

    for (int k0 = 0; k0 < K; k0 += 16) {
        int gk = k0 + kk;
        bool kok = gk < K;
#pragma unroll
        for (int p = 0; p < 4; ++p) {
            int mm = m0 + p * 16;
            int gm = bm + mm;
            As[kk][mm] = (kok && gm < M) ? A[(size_t)gm * lda + gk] : 0.f;
            int gn = bn + mm;
            Bs[kk][mm] = (kok && gn < N) ? B[(size_t)gn * ldb + gk] : 0.f;
        }
        __syncthreads();
#pragma unroll
        for (int k = 0; k < 16; ++k) {
            float4 av = *(const float4*)&As[k][ty * 4];
            float4 bv = *(const float4*)&Bs[k][tx * 4];
            acc[0][0] += av.x * bv.x; acc[0][1] += av.x * bv.y; acc[0][2] += av.x * bv.z; acc[0][3] += av.x * bv.w;
            acc[1][0] += av.y * bv.x; acc[1][1] += av.y * bv.y; acc[1][2] += av.y * bv.z; acc[1][3] += av.y * bv.w;
            acc[2][0] += av.z * bv.x; acc[2][1] += av.z * bv.y; acc[2][2] += av.z * bv.z; acc[2][3] += av.z * bv.w;
            acc[3][0] += av.w * bv.x; acc[3][1] += av.w * bv.y; acc[3][2] += av.w * bv.z; acc[3][3] += av.w * bv.w;
        }
        __syncthreads();
    }
#pragma unroll
    for (int i2 = 0; i2 < 4; ++i2) {
        int gm = bm + ty * 4 + i2;
        if (gm >= M) continue;
#pragma unroll
        for (int j = 0; j < 4; ++j) {
            int gn = bn + tx * 4 + j;
            if (gn >= N) continue;
            float v = acc[i2][j];
            if (act >= 1 && bias) v += bias[gn];
            if (act == 2) v = (v > 20.f) ? v : log1pf(__expf(v));
            C[(size_t)gm * ldc + gn] = v;
        }
    }
}

// ---------------------------------------------------------------- fused residual add + LayerNorm -> bf16
__global__ __launch_bounds__(256) void ln_resid_k(
    const float* __restrict__ hid, float* __restrict__ resid,
    ushort_t* __restrict__ hnb, const float* __restrict__ w,
    const float* __restrict__ b, int add)
{
    int wave = threadIdx.x >> 6, lane = threadIdx.x & 63;
    int row = blockIdx.x * 4 + wave;
    if (row >= M_ROWS) return;
    const float* hr = hid + (size_t)row * D_MODEL;
    float* rr = resid + (size_t)row * D_MODEL;
    float v[3];
#pragma unroll
    for (int j = 0; j < 3; ++j) {
        int e = lane + 64 * j;
        float h = hr[e];
        if (add) h += rr[e];
        rr[e] = h;
        v[j] = h;
    }
    float s = v[0] + v[1] + v[2];
    float sq = v[0] * v[0] + v[1] * v[1] + v[2] * v[2];
#pragma unroll
    for (int m = 1; m < 64; m <<= 1) {
        s += __shfl_xor(s, m, 64);
        sq += __shfl_xor(sq, m, 64);
    }
    float mu = s * (1.f / 192.f);
    float var = sq * (1.f / 192.f) - mu * mu;
    float ve = var + EPSV;
    float rs = rsqrtf(ve);
    rs = rs * (1.5f - 0.5f * ve * rs * rs);
    ushort_t* hnr = hnb + (size_t)row * D_MODEL;
#pragma unroll
    for (int j = 0; j < 3; ++j) {
        int e = lane + 64 * j;
        hnr[e] = f2bf((v[j] - mu) * rs * w[e] + b[e]);
    }
}

// ---------------------------------------------------------------- depthwise causal conv (k=4) + SiLU
__global__ __launch_bounds__(256) void conv_silu_k(
    const float* __restrict__ xz, const float* __restrict__ cw,
    const float* __restrict__ cb, float* __restrict__ xc)
{
    int idx = blockIdx.x * 256 + threadIdx.x;
    if (idx >= M_ROWS * D_INNER) return;
    int d = idx % D_INNER;
    int row = idx / D_INNER;
    int l = row % L_TOK;
    float acc = cb[d];
    const float* cwd = cw + d * 4;
#pragma unroll
    for (int k = 0; k < 4; ++k) {
        int ls = l + k - 3;
        if (ls >= 0) acc += xz[(size_t)(row + k - 3) * 768 + d] * cwd[k];
    }
    xc[idx] = silu_(acc);
}

// ================================================================ lane-per-channel chunked scan
// wave w -> (c = w/384, b = (w/6)%64, dg = w%6); lane owns d = dg*64+lane.
// h[16] per lane in regs; B_n/C_n broadcast via __shfl from per-lane dbc load.
// h_end/P/hs layout: [C][16][N_CH] (coalesced stores).

__global__ __launch_bounds__(256) void scan_p1(
    const float* __restrict__ delta, const float* __restrict__ xc,
    const float* __restrict__ dbc, const float* __restrict__ A_log,
    float* __restrict__ h_end, float* __restrict__ Pp, int clen)
{
    int w = blockIdx.x * 4 + (threadIdx.x >> 6);
    int lane = threadIdx.x & 63;
    int dg = w % 6, b = (w / 6) % 64, c = w / 384;
    int d = dg * 64 + lane;
    float Av[16];
#pragma unroll
    for (int n = 0; n < 16; ++n) Av[n] = -__expf(A_log[d * D_STATE + n]);
    float h[16], P[16];
#pragma unroll
    for (int n = 0; n < 16; ++n) { h[n] = 0.f; P[n] = 1.f; }

    size_t row0 = (size_t)b * L_TOK + (size_t)c * clen;
    const float* pd = delta + row0 * D_INNER + d;
    const float* px = xc + row0 * D_INNER + d;
    const float* pb = dbc + row0 * 44 + 12 + (lane & 31);
    float dl = *pd, xcv = *px, bc = *pb;
    for (int l = 0; l < clen; ++l) {
        int adv = (l + 1 < clen) ? 1 : 0;
        pd += adv * D_INNER; px += adv * D_INNER; pb += adv * 44;
        float dln = *pd, xcn = *px, bcn = *pb;
        float du = dl * xcv;
#pragma unroll
        for (int n = 0; n < 16; ++n) {
            float Bn = __shfl(bc, n, 64);
            float dA = __expf(dl * Av[n]);
            h[n] = dA * h[n] + du * Bn;
            P[n] *= dA;
        }
        dl = dln; xcv = xcn; bc = bcn;
    }
    int ch = b * D_INNER + d;
#pragma unroll
    for (int n = 0; n < 16; ++n) {
        size_t o = ((size_t)c * 16 + n) * N_CH + ch;
        h_end[o] = h[n];
        Pp[o] = P[n];
    }
}

__global__ __launch_bounds__(256) void scan_p2(
    const float* __restrict__ h_end, const float* __restrict__ Pp,
    float* __restrict__ hs, int nchunk)
{
    int idx = blockIdx.x * 256 + threadIdx.x;   // over 16*N_CH
    if (idx >= 16 * N_CH) return;
    float H = 0.f;
    hs[idx] = 0.f;
    for (int c = 0; c < nchunk - 1; ++c) {
        size_t o = (size_t)c * 16 * N_CH + idx;
        H = Pp[o] * H + h_end[o];
        hs[o + 16 * N_CH] = H;
    }
}

__global__ __launch_bounds__(256) void scan_p3(
    const float* __restrict__ delta, const float* __restrict__ xc,
    const float* __restrict__ dbc, const float* __restrict__ xz,
    const float* __restrict__ A_log, const float* __restrict__ Dp,
    const float* __restrict__ hs, ushort_t* __restrict__ yb, int clen)
{
    int w = blockIdx.x * 4 + (threadIdx.x >> 6);
    int lane = threadIdx.x & 63;
    int dg = w % 6, b = (w / 6) % 64, c = w / 384;
    int d = dg * 64 + lane;
    int ch = b * D_INNER + d;
    float Av[16];
#pragma unroll
    for (int n = 0; n < 16; ++n) Av[n] = -__expf(A_log[d * D_STATE + n]);
    float h[16];
#pragma unroll
    for (int n = 0; n < 16; ++n)
        h[n] = hs ? hs[((size_t)c * 16 + n) * N_CH + ch] : 0.f;
    float Dv = Dp[d];

    size_t row0 = (size_t)b * L_TOK + (size_t)c * clen;
    const float* pd = delta + row0 * D_INNER + d;
    const float* px = xc + row0 * D_INNER + d;
    const float* pb = dbc + row0 * 44 + 12 + (lane & 31);
    const float* pz = xz + row0 * 768 + D_INNER + d;
    ushort_t* py = yb + row0 * D_INNER + d;
    float dl = *pd, xcv = *px, bc = *pb, z = *pz;
    for (int l = 0; l < clen; ++l) {
        int adv = (l + 1 < clen) ? 1 : 0;
        pd += adv * D_INNER; px += adv * D_INNER; pb += adv * 44; pz += adv * 768;
        float dln = *pd, xcn = *px, bcn = *pb, zn = *pz;
        float du = dl * xcv;
        float y = 0.f;
#pragma unroll
        for (int n = 0; n < 16; ++n) {
            float Bn = __shfl(bc, n, 64);
            float Cn = __shfl(bc, 16 + n, 64);
            float dA = __expf(dl * Av[n]);
            h[n] = dA * h[n] + du * Bn;
            y += h[n] * Cn;
        }
        *py = f2bf((y + Dv * xcv) * silu_(z));
        py += D_INNER;
        dl = dln; xcv = xcn; bc = bcn; z = zn;
    }
}

// ---------------------------------------------------------------- final LN on last token only
__global__ __launch_bounds__(64) void final_ln_k(
    const float* __restrict__ hid, const float* __restrict__ w,
    const float* __restrict__ b, float* __restrict__ feat)
{
    int bb = blockIdx.x;
    int lane = threadIdx.x;
    const float* hr = hid + ((size_t)bb * L_TOK + (L_TOK - 1)) * D_MODEL;
    float v[3];
#pragma unroll
    for (int j = 0; j < 3; ++j) v[j] = hr[lane + 64 * j];
    float s = v[0] + v[1] + v[2];
    float sq = v[0] * v[0] + v[1] * v[1] + v[2] * v[2];
#pragma unroll
    for (int m = 1; m < 64; m <<= 1) {
        s += __shfl_xor(s, m, 64);
        sq += __shfl_xor(sq, m, 64);
    }
    float mu = s * (1.f / 192.f);
    float var = sq * (1.f / 192.f) - mu * mu;
    float ve = var + EPSV;
    float rs = rsqrtf(ve);
    rs = rs * (1.5f - 0.5f * ve * rs * rs);
#pragma unroll
    for (int j = 0; j < 3; ++j) {
        int e = lane + 64 * j;
        feat[(size_t)bb * D_MODEL + e] = (v[j] - mu) * rs * w[e] + b[e];
    }
}

// ================================================================ host
extern "C" void kernel_launch(void* const* d_in, const int* in_sizes, int n_in,
                              void* d_out, int out_size, void* d_ws, size_t ws_size,
                              hipStream_t stream) {
    const float* x         = (const float*)d_in[0];
    const float* patch_w   = (const float*)d_in[1];
    const float* patch_b   = (const float*)d_in[2];
    const float* norm_w    = (const float*)d_in[3];
    const float* norm_b    = (const float*)d_in[4];
    const float* in_proj_w = (const float*)d_in[5];
    const float* conv_w    = (const float*)d_in[6];
    const float* conv_b    = (const float*)d_in[7];
    const float* x_proj_w  = (const float*)d_in[8];
    const float* dt_proj_w = (const float*)d_in[9];
    const float* dt_proj_b = (const float*)d_in[10];
    const float* A_log     = (const float*)d_in[11];
    const float* Dp        = (const float*)d_in[12];
    const float* out_proj_w= (const float*)d_in[13];
    const float* normf_w   = (const float*)d_in[14];
    const float* normf_b   = (const float*)d_in[15];
    const float* head_w    = (const float*)d_in[16];
    const float* head_b    = (const float*)d_in[17];
    float* out = (float*)d_out;

    // ---- workspace layout (float units)
    float* ws = (float*)d_ws;
    size_t o = 0;
    float* resid = ws + o; o += (size_t)M_ROWS * D_MODEL;        // 2408448
    float* hid   = ws + o; o += (size_t)M_ROWS * D_MODEL;        // 2408448
    float* xz    = ws + o; o += (size_t)M_ROWS * 768;            // 9633792 (also hosts Acol bf16)
    float* xc    = ws + o; o += (size_t)M_ROWS * D_INNER;        // 4816896
    float* dbc   = ws + o; o += (size_t)M_ROWS * 44;             // 551936
    float* delta = ws + o; o += (size_t)M_ROWS * D_INNER;        // 4816896
    ushort_t* hnb = (ushort_t*)(ws + o); o += (size_t)M_ROWS * D_MODEL / 2;   // bf16
    ushort_t* yb  = (ushort_t*)(ws + o); o += (size_t)M_ROWS * D_INNER / 2;   // bf16
    ushort_t* iwb = (ushort_t*)(ws + o); o += (size_t)DEPTH * 768 * D_MODEL / 2;
    ushort_t* owb = (ushort_t*)(ws + o); o += (size_t)DEPTH * D_MODEL * D_INNER / 2;
    ushort_t* pwb = (ushort_t*)(ws + o); o += (size_t)D_MODEL * 768 / 2;
    float* feat  = ws + o; o += (size_t)BATCH * D_MODEL;
    float* scr   = ws + o;
    ushort_t* Acol = (ushort_t*)xz;

    // chunk count from remaining workspace
    size_t avail = (ws_size / 4 > o) ? (ws_size / 4 - o) : 0;
    int C = 1;
    const int cands[3] = {7, 4, 2};
    for (int ci = 0; ci < 3; ++ci) {
        size_t need = (size_t)cands[ci] * 16 * N_CH * 3;
        if (need <= avail) { C = cands[ci]; break; }
    }
    int clen = L_TOK / C;
    float* h_end = scr;
    float* Pp    = h_end + (size_t)C * 16 * N_CH;
    float* hs    = Pp    + (size_t)C * 16 * N_CH;

    // ---- weight conversion to bf16 (per launch; deterministic)
    f2bf_k<<<2048, 256, 0, stream>>>(in_proj_w, iwb, DEPTH * 768 * D_MODEL);
    f2bf_k<<<2048, 256, 0, stream>>>(out_proj_w, owb, DEPTH * D_MODEL * D_INNER);
    f2bf_k<<<576, 256, 0, stream>>>(patch_w, pwb, D_MODEL * 768);

    // ---- patch embedding: im2col(bf16) + MFMA GEMM -> hid
    im2col_k<<<(M_ROWS * 768) / 256, 256, 0, stream>>>(x, Acol);
    {
        dim3 g(D_MODEL / 64, M_ROWS / 128);
        gemm_mfma<<<g, 256, 0, stream>>>(Acol, 768, pwb, 768, hid, D_MODEL,
                                         D_MODEL, 768, patch_b);
    }

    // ---- 24 mamba layers
    for (int i = 0; i < DEPTH; ++i) {
        const float* nw  = norm_w    + (size_t)i * D_MODEL;
        const float* nb  = norm_b    + (size_t)i * D_MODEL;
        const ushort_t* iw = iwb     + (size_t)i * 768 * D_MODEL;
        const float* cwp = conv_w    + (size_t)i * D_INNER * 4;
        const float* cbp = conv_b    + (size_t)i * D_INNER;
        const float* xw  = x_proj_w  + (size_t)i * 44 * D_INNER;
        const float* dtw = dt_proj_w + (size_t)i * D_INNER * DT_RANK;
        const float* dtb = dt_proj_b + (size_t)i * D_INNER;
        const float* al  = A_log     + (size_t)i * D_INNER * D_STATE;
        const float* dp  = Dp        + (size_t)i * D_INNER;
        const ushort_t* ow = owb     + (size_t)i * D_MODEL * D_INNER;

        // residual + LN -> bf16
        ln_resid_k<<<M_ROWS / 4, 256, 0, stream>>>(hid, resid, hnb, nw, nb, i > 0 ? 1 : 0);

        // in_proj: xz[M,768] = hnb @ iw^T  (MFMA)
        {
            dim3 g(768 / 64, M_ROWS / 128);
            gemm_mfma<<<g, 256, 0, stream>>>(hnb, D_MODEL, iw, D_MODEL, xz, 768,
                                             768, D_MODEL, nullptr);
        }
        // conv + silu -> xc (fp32)
        conv_silu_k<<<(M_ROWS * D_INNER) / 256, 256, 0, stream>>>(xz, cwp, cbp, xc);
        // x_proj: dbc[M,44] = xc @ xw^T (fp32)
        {
            dim3 g(1, M_ROWS / 64);
            gemm_nt<<<g, 256, 0, stream>>>(xc, D_INNER, xw, D_INNER, dbc, 44,
                                           M_ROWS, 44, D_INNER, nullptr, 0);
        }
        // dt_proj + softplus -> delta (fp32)
        {
            dim3 g(D_INNER / 64, M_ROWS / 64);
            gemm_nt<<<g, 256, 0, stream>>>(dbc, 44, dtw, DT_RANK, delta, D_INNER,
                                           M_ROWS, D_INNER, DT_RANK, dtb, 2);
        }
        // lane-per-channel chunked scan -> yb (bf16)
        if (C > 1) {
            scan_p1<<<96 * C, 256, 0, stream>>>(delta, xc, dbc, al, h_end, Pp, clen);
            scan_p2<<<(16 * N_CH) / 256, 256, 0, stream>>>(h_end, Pp, hs, C);
            scan_p3<<<96 * C, 256, 0, stream>>>(delta, xc, dbc, xz, al, dp, hs, yb, clen);
        } else {
            scan_p3<<<96, 256, 0, stream>>>(delta, xc, dbc, xz, al, dp, nullptr, yb, clen);
        }
        // out_proj: hid[M,192] = yb @ ow^T  (MFMA)
        {
            dim3 g(D_MODEL / 64, M_ROWS / 128);
            gemm_mfma<<<g, 256, 0, stream>>>(yb, D_INNER, ow, D_INNER, hid, D_MODEL,
                                             D_MODEL, D_INNER, nullptr);
        }
    }

    // ---- final LN (last token) + head
    final_ln_k<<<BATCH, 64, 0, stream>>>(hid, normf_w, normf_b, feat);
    {
        dim3 g((NCLS + 63) / 64, (BATCH + 63) / 64);
        gemm_nt<<<g, 256, 0, stream>>>(feat, D_MODEL, head_w, D_MODEL, out, NCLS,
                                       BATCH, NCLS, D_MODEL, head_b, 1);
    }
}

// Round 4
// 4205.174 us; speedup vs baseline: 2.3091x; 1.1664x over previous
//
#include <hip/hip_runtime.h>
#include <hip/hip_bf16.h>
#include <math.h>

#define DEPTH 24
#define D_MODEL 192
#define D_INNER 384
#define D_STATE 16
#define DT_RANK 12
#define NCLS 1000
#define PATCHSZ 16
#define IMG 224
#define GSZ 14
#define L_TOK 196
#define BATCH 64
#define M_ROWS (BATCH*L_TOK)   // 12544
#define N_CH (BATCH*D_INNER)   // 24576
#define EPSV 1e-5f

typedef __attribute__((ext_vector_type(8))) short bf16x8;
typedef __attribute__((ext_vector_type(4))) float f32x4;
typedef unsigned short ushort_t;
typedef unsigned int uint_t;

__device__ __forceinline__ float silu_(float x) { return x / (1.f + __expf(-x)); }

__device__ __forceinline__ ushort_t f2bf(float f) {
    uint_t u = __float_as_uint(f);
    u += 0x7fffu + ((u >> 16) & 1u);       // RNE
    return (ushort_t)(u >> 16);
}

// ---------------------------------------------------------------- fp32 -> bf16 convert
__global__ __launch_bounds__(256) void f2bf_k(const float* __restrict__ s,
                                              ushort_t* __restrict__ d, int n) {
    for (int i = blockIdx.x * 256 + threadIdx.x; i < n; i += gridDim.x * 256)
        d[i] = f2bf(s[i]);
}

// ---- pad x_proj_w (DEPTH,44,384) -> (DEPTH,64,384) bf16, rows 44..63 = 0
__global__ __launch_bounds__(256) void pad_xw_k(const float* __restrict__ s,
                                                ushort_t* __restrict__ d) {
    int idx = blockIdx.x * 256 + threadIdx.x;
    if (idx >= DEPTH * 64 * 384) return;
    int k = idx % 384, r = idx / 384;
    int n = r % 64, i = r / 64;
    d[idx] = (n < 44) ? f2bf(s[((size_t)i * 44 + n) * 384 + k]) : (ushort_t)0;
}

// ---- pad dt_proj_w (DEPTH,384,12) -> (DEPTH,384,32) bf16, cols 12..31 = 0
__global__ __launch_bounds__(256) void pad_dtw_k(const float* __restrict__ s,
                                                 ushort_t* __restrict__ d) {
    int idx = blockIdx.x * 256 + threadIdx.x;
    if (idx >= DEPTH * 384 * 32) return;
    int rr = idx % 32, q = idx / 32;
    int dd = q % 384, i = q / 384;
    d[idx] = (rr < 12) ? f2bf(s[((size_t)i * 384 + dd) * 12 + rr]) : (ushort_t)0;
}

// ---------------------------------------------------------------- im2col (bf16 out)
__global__ __launch_bounds__(256) void im2col_k(const float* __restrict__ x,
                                                ushort_t* __restrict__ Acol) {
    int idx = blockIdx.x * 256 + threadIdx.x;
    if (idx >= M_ROWS * 768) return;
    int row = idx / 768, k = idx % 768;
    int b = row / L_TOK, l = row % L_TOK;
    int i = l / GSZ, j = l % GSZ;
    int c = k >> 8, r = k & 255, p = r >> 4, q = r & 15;
    Acol[idx] = f2bf(x[((size_t)(b * 3 + c) * IMG + (i * PATCHSZ + p)) * IMG + (j * PATCHSZ + q)]);
}

// ---------------------------------------------------------------- bf16 MFMA GEMM
// C[M,N] fp32 = A[M,K]bf16 * B[N,K]bf16^T (+bias, act: 0 none, 1 bias, 2 bias+softplus).
// Stores only cols < nvalid. Optionally writes dtpad[M,32] bf16 (cols<12 = val, 12..31 = 0).
// M%128==0, N%64==0, K%32==0. block 256 = 4 waves (2x2), tile 128x64, BK=32.
__global__ __launch_bounds__(256) void gemm_mfma(
    const ushort_t* __restrict__ A, int lda,
    const ushort_t* __restrict__ B, int ldb,
    float* __restrict__ C, int ldc,
    int N, int K, const float* __restrict__ bias, int act, int nvalid,
    ushort_t* __restrict__ dtpad)
{
    __shared__ uint4 AlsU[512];   // 128 x 32 bf16, swizzled
    __shared__ uint4 BlsU[256];   // 64 x 32 bf16, swizzled
    char* Als = (char*)AlsU;
    char* Bls = (char*)BlsU;
    const int t = threadIdx.x;
    const int wid = t >> 6, lane = t & 63;
    const int wm = wid >> 1, wn = wid & 1;
    const int l15 = lane & 15, l4 = lane >> 4;
    const int bm = blockIdx.y * 128, bn = blockIdx.x * 64;

    f32x4 acc[4][2];
#pragma unroll
    for (int i = 0; i < 4; ++i)
#pragma unroll
        for (int j = 0; j < 2; ++j) acc[i][j] = (f32x4){0.f, 0.f, 0.f, 0.f};

    const int arow = t >> 2, akb = t & 3;
    for (int k0 = 0; k0 < K; k0 += 32) {
#pragma unroll
        for (int it = 0; it < 2; ++it) {
            int c = t + it * 256;
            int row = c >> 2, kb = c & 3;
            uint4 v = *(const uint4*)(A + (size_t)(bm + row) * lda + k0 + kb * 8);
            *(uint4*)(Als + row * 64 + ((kb ^ (row & 3)) << 4)) = v;
        }
        {
            uint4 v = *(const uint4*)(B + (size_t)(bn + arow) * ldb + k0 + akb * 8);
            *(uint4*)(Bls + arow * 64 + ((akb ^ (arow & 3)) << 4)) = v;
        }
        __syncthreads();
        bf16x8 af[4], bfr[2];
#pragma unroll
        for (int fm = 0; fm < 4; ++fm) {
            int row = wm * 64 + fm * 16 + l15;
            af[fm] = *(const bf16x8*)(Als + row * 64 + ((l4 ^ (row & 3)) << 4));
        }
#pragma unroll
        for (int fn = 0; fn < 2; ++fn) {
            int row = wn * 32 + fn * 16 + l15;
            bfr[fn] = *(const bf16x8*)(Bls + row * 64 + ((l4 ^ (row & 3)) << 4));
        }
#pragma unroll
        for (int fm = 0; fm < 4; ++fm)
#pragma unroll
            for (int fn = 0; fn < 2; ++fn)
                acc[fm][fn] = __builtin_amdgcn_mfma_f32_16x16x32_bf16(af[fm], bfr[fn], acc[fm][fn], 0, 0, 0);
        __syncthreads();
    }
    // epilogue: frag row=(l>>4)*4+r, col=l&15
#pragma unroll
    for (int fn = 0; fn < 2; ++fn) {
        int col = bn + wn * 32 + fn * 16 + l15;
        float bv = (act >= 1 && bias) ? bias[col] : 0.f;
        bool cok = col < nvalid;
        bool dtc = dtpad && (col < 32);
#pragma unroll
        for (int fm = 0; fm < 4; ++fm) {
#pragma unroll
            for (int r = 0; r < 4; ++r) {
                int row = bm + wm * 64 + fm * 16 + l4 * 4 + r;
                float v = acc[fm][fn][r] + bv;
                if (act == 2) v = (v > 20.f) ? v : log1pf(__expf(v));
                if (cok) C[(size_t)row * ldc + col] = v;
                if (dtc) dtpad[(size_t)row * 32 + col] = (col < 12) ? f2bf(v) : (ushort_t)0;
            }
        }
    }
}

// ---------------------------------------------------------------- generic fp32 GEMM (head only)
__global__ __launch_bounds__(256) void gemm_nt(
    const float* __restrict__ A, int lda,
    const float* __restrict__ B, int ldb,
    float* __restrict__ C, int ldc,
    int M, int N, int K,
    const float* __restrict__ bias, int act)
{
    __shared__ float As[16][68];
    __shared__ float Bs[16][68];
    const int t = threadIdx.x;
    const int tx = t & 15, ty = t >> 4;
    const int bm = blockIdx.y * 64, bn = blockIdx.x * 64;
    float acc[4][4] = {};
    const int kk = t & 15, m0 = t >> 4;

    for (int k0 = 0; k0 < K; k0 += 16) {
        int gk = k0 + kk;
        bool kok = gk < K;
#pragma unroll
        for (int p = 0; p < 4; ++p) {
            int mm = m0 + p * 16;
            int gm = bm + mm;
            As[kk][mm] = (kok && gm < M) ? A[(size_t)gm * lda + gk] : 0.f;
            int gn = bn + mm;
            Bs[kk][mm] = (kok && gn < N) ? B[(size_t)gn * ldb + gk] : 0.f;
        }
        __syncthreads();
#pragma unroll
        for (int k = 0; k < 16; ++k) {
            float4 av = *(const float4*)&As[k][ty * 4];
            float4 bv = *(const float4*)&Bs[k][tx * 4];
            acc[0][0] += av.x * bv.x; acc[0][1] += av.x * bv.y; acc[0][2] += av.x * bv.z; acc[0][3] += av.x * bv.w;
            acc[1][0] += av.y * bv.x; acc[1][1] += av.y * bv.y; acc[1][2] += av.y * bv.z; acc[1][3] += av.y * bv.w;
            acc[2][0] += av.z * bv.x; acc[2][1] += av.z * bv.y; acc[2][2] += av.z * bv.z; acc[2][3] += av.z * bv.w;
            acc[3][0] += av.w * bv.x; acc[3][1] += av.w * bv.y; acc[3][2] += av.w * bv.z; acc[3][3] += av.w * bv.w;
        }
        __syncthreads();
    }
#pragma unroll
    for (int i2 = 0; i2 < 4; ++i2) {
        int gm = bm + ty * 4 + i2;
        if (gm >= M) continue;
#pragma unroll
        for (int j = 0; j < 4; ++j) {
            int gn = bn + tx * 4 + j;
            if (gn >= N) continue;
            float v = acc[i2][j];
            if (act >= 1 && bias) v += bias[gn];
            if (act == 2) v = (v > 20.f) ? v : log1pf(__expf(v));
            C[(size_t)gm * ldc + gn] = v;
        }
    }
}

// ---------------------------------------------------------------- fused residual add + LayerNorm -> bf16
__global__ __launch_bounds__(256) void ln_resid_k(
    const float* __restrict__ hid, float* __restrict__ resid,
    ushort_t* __restrict__ hnb, const float* __restrict__ w,
    const float* __restrict__ b, int add)
{
    int wave = threadIdx.x >> 6, lane = threadIdx.x & 63;
    int row = blockIdx.x * 4 + wave;
    if (row >= M_ROWS) return;
    const float* hr = hid + (size_t)row * D_MODEL;
    float* rr = resid + (size_t)row * D_MODEL;
    float v[3];
#pragma unroll
    for (int j = 0; j < 3; ++j) {
        int e = lane + 64 * j;
        float h = hr[e];
        if (add) h += rr[e];
        rr[e] = h;
        v[j] = h;
    }
    float s = v[0] + v[1] + v[2];
    float sq = v[0] * v[0] + v[1] * v[1] + v[2] * v[2];
#pragma unroll
    for (int m = 1; m < 64; m <<= 1) {
        s += __shfl_xor(s, m, 64);
        sq += __shfl_xor(sq, m, 64);
    }
    float mu = s * (1.f / 192.f);
    float var = sq * (1.f / 192.f) - mu * mu;
    float ve = var + EPSV;
    float rs = rsqrtf(ve);
    rs = rs * (1.5f - 0.5f * ve * rs * rs);
    ushort_t* hnr = hnb + (size_t)row * D_MODEL;
#pragma unroll
    for (int j = 0; j < 3; ++j) {
        int e = lane + 64 * j;
        hnr[e] = f2bf((v[j] - mu) * rs * w[e] + b[e]);
    }
}

// ---------------------------------------------------------------- depthwise causal conv (k=4) + SiLU (fp32 + bf16 out)
__global__ __launch_bounds__(256) void conv_silu_k(
    const float* __restrict__ xz, const float* __restrict__ cw,
    const float* __restrict__ cb, float* __restrict__ xc,
    ushort_t* __restrict__ xcb)
{
    int idx = blockIdx.x * 256 + threadIdx.x;
    if (idx >= M_ROWS * D_INNER) return;
    int d = idx % D_INNER;
    int row = idx / D_INNER;
    int l = row % L_TOK;
    float acc = cb[d];
    const float* cwd = cw + d * 4;
#pragma unroll
    for (int k = 0; k < 4; ++k) {
        int ls = l + k - 3;
        if (ls >= 0) acc += xz[(size_t)(row + k - 3) * 768 + d] * cwd[k];
    }
    float v = silu_(acc);
    xc[idx] = v;
    xcb[idx] = f2bf(v);
}

// ================================================================ lane-per-channel chunked scan
__global__ __launch_bounds__(256) void scan_p1(
    const float* __restrict__ delta, const float* __restrict__ xc,
    const float* __restrict__ dbc, const float* __restrict__ A_log,
    float* __restrict__ h_end, float* __restrict__ Pp, int clen)
{
    int w = blockIdx.x * 4 + (threadIdx.x >> 6);
    int lane = threadIdx.x & 63;
    int dg = w % 6, b = (w / 6) % 64, c = w / 384;
    int d = dg * 64 + lane;
    float Av[16];
#pragma unroll
    for (int n = 0; n < 16; ++n) Av[n] = -__expf(A_log[d * D_STATE + n]);
    float h[16], P[16];
#pragma unroll
    for (int n = 0; n < 16; ++n) { h[n] = 0.f; P[n] = 1.f; }

    size_t row0 = (size_t)b * L_TOK + (size_t)c * clen;
    const float* pd = delta + row0 * D_INNER + d;
    const float* px = xc + row0 * D_INNER + d;
    const float* pb = dbc + row0 * 44 + 12 + (lane & 31);
    float dl = *pd, xcv = *px, bc = *pb;
    for (int l = 0; l < clen; ++l) {
        int adv = (l + 1 < clen) ? 1 : 0;
        pd += adv * D_INNER; px += adv * D_INNER; pb += adv * 44;
        float dln = *pd, xcn = *px, bcn = *pb;
        float du = dl * xcv;
#pragma unroll
        for (int n = 0; n < 16; ++n) {
            float Bn = __shfl(bc, n, 64);
            float dA = __expf(dl * Av[n]);
            h[n] = dA * h[n] + du * Bn;
            P[n] *= dA;
        }
        dl = dln; xcv = xcn; bc = bcn;
    }
    int ch = b * D_INNER + d;
#pragma unroll
    for (int n = 0; n < 16; ++n) {
        size_t o = ((size_t)c * 16 + n) * N_CH + ch;
        h_end[o] = h[n];
        Pp[o] = P[n];
    }
}

__global__ __launch_bounds__(256) void scan_p2(
    const float* __restrict__ h_end, const float* __restrict__ Pp,
    float* __restrict__ hs, int nchunk)
{
    int idx = blockIdx.x * 256 + threadIdx.x;
    if (idx >= 16 * N_CH) return;
    float H = 0.f;
    hs[idx] = 0.f;
    for (int c = 0; c < nchunk - 1; ++c) {
        size_t o = (size_t)c * 16 * N_CH + idx;
        H = Pp[o] * H + h_end[o];
        hs[o + 16 * N_CH] = H;
    }
}

__global__ __launch_bounds__(256) void scan_p3(
    const float* __restrict__ delta, const float* __restrict__ xc,
    const float* __restrict__ dbc, const float* __restrict__ xz,
    const float* __restrict__ A_log, const float* __restrict__ Dp,
    const float* __restrict__ hs, ushort_t* __restrict__ yb, int clen)
{
    int w = blockIdx.x * 4 + (threadIdx.x >> 6);
    int lane = threadIdx.x & 63;
    int dg = w % 6, b = (w / 6) % 64, c = w / 384;
    int d = dg * 64 + lane;
    int ch = b * D_INNER + d;
    float Av[16];
#pragma unroll
    for (int n = 0; n < 16; ++n) Av[n] = -__expf(A_log[d * D_STATE + n]);
    float h[16];
#pragma unroll
    for (int n = 0; n < 16; ++n)
        h[n] = hs ? hs[((size_t)c * 16 + n) * N_CH + ch] : 0.f;
    float Dv = Dp[d];

    size_t row0 = (size_t)b * L_TOK + (size_t)c * clen;
    const float* pd = delta + row0 * D_INNER + d;
    const float* px = xc + row0 * D_INNER + d;
    const float* pb = dbc + row0 * 44 + 12 + (lane & 31);
    const float* pz = xz + row0 * 768 + D_INNER + d;
    ushort_t* py = yb + row0 * D_INNER + d;
    float dl = *pd, xcv = *px, bc = *pb, z = *pz;
    for (int l = 0; l < clen; ++l) {
        int adv = (l + 1 < clen) ? 1 : 0;
        pd += adv * D_INNER; px += adv * D_INNER; pb += adv * 44; pz += adv * 768;
        float dln = *pd, xcn = *px, bcn = *pb, zn = *pz;
        float du = dl * xcv;
        float y = 0.f;
#pragma unroll
        for (int n = 0; n < 16; ++n) {
            float Bn = __shfl(bc, n, 64);
            float Cn = __shfl(bc, 16 + n, 64);
            float dA = __expf(dl * Av[n]);
            h[n] = dA * h[n] + du * Bn;
            y += h[n] * Cn;
        }
        *py = f2bf((y + Dv * xcv) * silu_(z));
        py += D_INNER;
        dl = dln; xcv = xcn; bc = bcn; z = zn;
    }
}

// ---------------------------------------------------------------- final LN on last token only
__global__ __launch_bounds__(64) void final_ln_k(
    const float* __restrict__ hid, const float* __restrict__ w,
    const float* __restrict__ b, float* __restrict__ feat)
{
    int bb = blockIdx.x;
    int lane = threadIdx.x;
    const float* hr = hid + ((size_t)bb * L_TOK + (L_TOK - 1)) * D_MODEL;
    float v[3];
#pragma unroll
    for (int j = 0; j < 3; ++j) v[j] = hr[lane + 64 * j];
    float s = v[0] + v[1] + v[2];
    float sq = v[0] * v[0] + v[1] * v[1] + v[2] * v[2];
#pragma unroll
    for (int m = 1; m < 64; m <<= 1) {
        s += __shfl_xor(s, m, 64);
        sq += __shfl_xor(sq, m, 64);
    }
    float mu = s * (1.f / 192.f);
    float var = sq * (1.f / 192.f) - mu * mu;
    float ve = var + EPSV;
    float rs = rsqrtf(ve);
    rs = rs * (1.5f - 0.5f * ve * rs * rs);
#pragma unroll
    for (int j = 0; j < 3; ++j) {
        int e = lane + 64 * j;
        feat[(size_t)bb * D_MODEL + e] = (v[j] - mu) * rs * w[e] + b[e];
    }
}

// ================================================================ host
extern "C" void kernel_launch(void* const* d_in, const int* in_sizes, int n_in,
                              void* d_out, int out_size, void* d_ws, size_t ws_size,
                              hipStream_t stream) {
    const float* x         = (const float*)d_in[0];
    const float* patch_w   = (const float*)d_in[1];
    const float* patch_b   = (const float*)d_in[2];
    const float* norm_w    = (const float*)d_in[3];
    const float* norm_b    = (const float*)d_in[4];
    const float* in_proj_w = (const float*)d_in[5];
    const float* conv_w    = (const float*)d_in[6];
    const float* conv_b    = (const float*)d_in[7];
    const float* x_proj_w  = (const float*)d_in[8];
    const float* dt_proj_w = (const float*)d_in[9];
    const float* dt_proj_b = (const float*)d_in[10];
    const float* A_log     = (const float*)d_in[11];
    const float* Dp        = (const float*)d_in[12];
    const float* out_proj_w= (const float*)d_in[13];
    const float* normf_w   = (const float*)d_in[14];
    const float* normf_b   = (const float*)d_in[15];
    const float* head_w    = (const float*)d_in[16];
    const float* head_b    = (const float*)d_in[17];
    float* out = (float*)d_out;

    // ---- workspace layout (float units)
    float* ws = (float*)d_ws;
    size_t o = 0;
    float* resid = ws + o; o += (size_t)M_ROWS * D_MODEL;
    float* hid   = ws + o; o += (size_t)M_ROWS * D_MODEL;
    float* xz    = ws + o; o += (size_t)M_ROWS * 768;            // also hosts Acol bf16
    float* xc    = ws + o; o += (size_t)M_ROWS * D_INNER;
    float* dbc   = ws + o; o += (size_t)M_ROWS * 44;
    float* delta = ws + o; o += (size_t)M_ROWS * D_INNER;
    ushort_t* hnb = (ushort_t*)(ws + o); o += (size_t)M_ROWS * D_MODEL / 2;
    ushort_t* yb  = (ushort_t*)(ws + o); o += (size_t)M_ROWS * D_INNER / 2;
    ushort_t* xcb = (ushort_t*)(ws + o); o += (size_t)M_ROWS * D_INNER / 2;
    ushort_t* dtpadb = (ushort_t*)(ws + o); o += (size_t)M_ROWS * 32 / 2;
    ushort_t* iwb = (ushort_t*)(ws + o); o += (size_t)DEPTH * 768 * D_MODEL / 2;
    ushort_t* owb = (ushort_t*)(ws + o); o += (size_t)DEPTH * D_MODEL * D_INNER / 2;
    ushort_t* pwb = (ushort_t*)(ws + o); o += (size_t)D_MODEL * 768 / 2;
    ushort_t* xwb = (ushort_t*)(ws + o); o += (size_t)DEPTH * 64 * 384 / 2;
    ushort_t* dtwb = (ushort_t*)(ws + o); o += (size_t)DEPTH * 384 * 32 / 2;
    float* feat  = ws + o; o += (size_t)BATCH * D_MODEL;
    float* scr   = ws + o;
    ushort_t* Acol = (ushort_t*)xz;

    // chunk count from remaining workspace
    size_t avail = (ws_size / 4 > o) ? (ws_size / 4 - o) : 0;
    int C = 1;
    const int cands[3] = {7, 4, 2};
    for (int ci = 0; ci < 3; ++ci) {
        size_t need = (size_t)cands[ci] * 16 * N_CH * 3;
        if (need <= avail) { C = cands[ci]; break; }
    }
    int clen = L_TOK / C;
    float* h_end = scr;
    float* Pp    = h_end + (size_t)C * 16 * N_CH;
    float* hs    = Pp    + (size_t)C * 16 * N_CH;

    // ---- weight conversion to bf16 (per launch; deterministic)
    f2bf_k<<<2048, 256, 0, stream>>>(in_proj_w, iwb, DEPTH * 768 * D_MODEL);
    f2bf_k<<<2048, 256, 0, stream>>>(out_proj_w, owb, DEPTH * D_MODEL * D_INNER);
    f2bf_k<<<576, 256, 0, stream>>>(patch_w, pwb, D_MODEL * 768);
    pad_xw_k<<<(DEPTH * 64 * 384) / 256, 256, 0, stream>>>(x_proj_w, xwb);
    pad_dtw_k<<<(DEPTH * 384 * 32) / 256, 256, 0, stream>>>(dt_proj_w, dtwb);

    // ---- patch embedding: im2col(bf16) + MFMA GEMM -> hid
    im2col_k<<<(M_ROWS * 768) / 256, 256, 0, stream>>>(x, Acol);
    {
        dim3 g(D_MODEL / 64, M_ROWS / 128);
        gemm_mfma<<<g, 256, 0, stream>>>(Acol, 768, pwb, 768, hid, D_MODEL,
                                         D_MODEL, 768, patch_b, 1, D_MODEL, nullptr);
    }

    // ---- 24 mamba layers
    for (int i = 0; i < DEPTH; ++i) {
        const float* nw  = norm_w    + (size_t)i * D_MODEL;
        const float* nb  = norm_b    + (size_t)i * D_MODEL;
        const ushort_t* iw = iwb     + (size_t)i * 768 * D_MODEL;
        const float* cwp = conv_w    + (size_t)i * D_INNER * 4;
        const float* cbp = conv_b    + (size_t)i * D_INNER;
        const ushort_t* xwl = xwb    + (size_t)i * 64 * 384;
        const ushort_t* dtwl = dtwb  + (size_t)i * 384 * 32;
        const float* dtb = dt_proj_b + (size_t)i * D_INNER;
        const float* al  = A_log     + (size_t)i * D_INNER * D_STATE;
        const float* dp  = Dp        + (size_t)i * D_INNER;
        const ushort_t* ow = owb     + (size_t)i * D_MODEL * D_INNER;

        // residual + LN -> bf16
        ln_resid_k<<<M_ROWS / 4, 256, 0, stream>>>(hid, resid, hnb, nw, nb, i > 0 ? 1 : 0);

        // in_proj: xz[M,768] = hnb @ iw^T  (MFMA)
        {
            dim3 g(768 / 64, M_ROWS / 128);
            gemm_mfma<<<g, 256, 0, stream>>>(hnb, D_MODEL, iw, D_MODEL, xz, 768,
                                             768, D_MODEL, nullptr, 0, 768, nullptr);
        }
        // conv + silu -> xc (fp32) + xcb (bf16)
        conv_silu_k<<<(M_ROWS * D_INNER) / 256, 256, 0, stream>>>(xz, cwp, cbp, xc, xcb);
        // x_proj (MFMA): dbc[M,44] = xcb @ xwl^T ; also emits dtpadb[M,32] bf16
        {
            dim3 g(1, M_ROWS / 128);
            gemm_mfma<<<g, 256, 0, stream>>>(xcb, D_INNER, xwl, D_INNER, dbc, 44,
                                             64, D_INNER, nullptr, 0, 44, dtpadb);
        }
        // dt_proj (MFMA): delta[M,384] = softplus(dtpadb @ dtwl^T + dtb)
        {
            dim3 g(D_INNER / 64, M_ROWS / 128);
            gemm_mfma<<<g, 256, 0, stream>>>(dtpadb, 32, dtwl, 32, delta, D_INNER,
                                             D_INNER, 32, dtb, 2, D_INNER, nullptr);
        }
        // lane-per-channel chunked scan -> yb (bf16)
        if (C > 1) {
            scan_p1<<<96 * C, 256, 0, stream>>>(delta, xc, dbc, al, h_end, Pp, clen);
            scan_p2<<<(16 * N_CH) / 256, 256, 0, stream>>>(h_end, Pp, hs, C);
            scan_p3<<<96 * C, 256, 0, stream>>>(delta, xc, dbc, xz, al, dp, hs, yb, clen);
        } else {
            scan_p3<<<96, 256, 0, stream>>>(delta, xc, dbc, xz, al, dp, nullptr, yb, clen);
        }
        // out_proj: hid[M,192] = yb @ ow^T  (MFMA)
        {
            dim3 g(D_MODEL / 64, M_ROWS / 128);
            gemm_mfma<<<g, 256, 0, stream>>>(yb, D_INNER, ow, D_INNER, hid, D_MODEL,
                                             D_MODEL, D_INNER, nullptr, 0, D_MODEL, nullptr);
        }
    }

    // ---- final LN (last token) + head
    final_ln_k<<<BATCH, 64, 0, stream>>>(hid, normf_w, normf_b, feat);
    {
        dim3 g((NCLS + 63) / 64, (BATCH + 63) / 64);
        gemm_nt<<<g, 256, 0, stream>>>(feat, D_MODEL, head_w, D_MODEL, out, NCLS,
                                       BATCH, NCLS, D_MODEL, head_b, 1);
    }
}